// Round 1
// baseline (2364.600 us; speedup 1.0000x reference)
//
#include <hip/hip_runtime.h>

#define Bn 4
#define Sn 2048
#define Dn 1024
#define Hn 16
#define HDn 64
#define MROWS (Bn * Sn)   // 8192

// ---------------------------------------------------------------------------
// NT GEMM: C[m][n] = sum_k A[m][k] * W[n][k] + bias[n]
// BM=BN=128, BK=16, 256 threads, per-thread 8x8 (2x2 blocks of 4x4).
// MODE 0: C[m*Dn + n]   (plain row-major, N == Dn)
// MODE 1: head-interleave: out[((b*Hn+h)*Sn+s)*64 + d], m=b*Sn+s, n=h*64+d
// ---------------------------------------------------------------------------
template<int MODE>
__global__ __launch_bounds__(256)
void gemm_nt(const float* __restrict__ A, const float* __restrict__ W,
             const float* __restrict__ bias, float* __restrict__ C)
{
    __shared__ float As[16][128];   // k-major
    __shared__ float Bs[16][128];   // k-major
    const int tid = threadIdx.x;
    const int tx = tid & 15, ty = tid >> 4;
    const int n0 = blockIdx.x * 128;
    const int m0 = blockIdx.y * 128;
    const int r  = tid >> 2;          // 0..63
    const int c4 = (tid & 3) << 2;    // 0,4,8,12
    const int K  = Dn;

    float acc[8][8];
#pragma unroll
    for (int i = 0; i < 8; ++i)
#pragma unroll
        for (int j = 0; j < 8; ++j) acc[i][j] = 0.f;

    const float* Arow0 = A + (size_t)(m0 + r) * K + c4;
    const float* Arow1 = A + (size_t)(m0 + 64 + r) * K + c4;
    const float* Wrow0 = W + (size_t)(n0 + r) * K + c4;
    const float* Wrow1 = W + (size_t)(n0 + 64 + r) * K + c4;

    for (int k0 = 0; k0 < K; k0 += 16) {
        const float4 a0 = *(const float4*)(Arow0 + k0);
        const float4 a1 = *(const float4*)(Arow1 + k0);
        const float4 w0 = *(const float4*)(Wrow0 + k0);
        const float4 w1 = *(const float4*)(Wrow1 + k0);
        __syncthreads();
        As[c4+0][r]    = a0.x; As[c4+1][r]    = a0.y; As[c4+2][r]    = a0.z; As[c4+3][r]    = a0.w;
        As[c4+0][64+r] = a1.x; As[c4+1][64+r] = a1.y; As[c4+2][64+r] = a1.z; As[c4+3][64+r] = a1.w;
        Bs[c4+0][r]    = w0.x; Bs[c4+1][r]    = w0.y; Bs[c4+2][r]    = w0.z; Bs[c4+3][r]    = w0.w;
        Bs[c4+0][64+r] = w1.x; Bs[c4+1][64+r] = w1.y; Bs[c4+2][64+r] = w1.z; Bs[c4+3][64+r] = w1.w;
        __syncthreads();
#pragma unroll
        for (int k = 0; k < 16; ++k) {
            const float4 av0 = *(const float4*)&As[k][ty << 2];
            const float4 av1 = *(const float4*)&As[k][64 + (ty << 2)];
            const float4 bv0 = *(const float4*)&Bs[k][tx << 2];
            const float4 bv1 = *(const float4*)&Bs[k][64 + (tx << 2)];
            const float a[8] = {av0.x, av0.y, av0.z, av0.w, av1.x, av1.y, av1.z, av1.w};
            const float b[8] = {bv0.x, bv0.y, bv0.z, bv0.w, bv1.x, bv1.y, bv1.z, bv1.w};
#pragma unroll
            for (int i = 0; i < 8; ++i)
#pragma unroll
                for (int j = 0; j < 8; ++j)
                    acc[i][j] += a[i] * b[j];
        }
    }

#pragma unroll
    for (int i = 0; i < 8; ++i) {
        const int row = m0 + ((i & 4) << 4) + (ty << 2) + (i & 3);
#pragma unroll
        for (int q = 0; q < 2; ++q) {
            const int col = n0 + q * 64 + (tx << 2);
            const float4 bv = *(const float4*)&bias[col];
            float4 v;
            v.x = acc[i][q*4+0] + bv.x;
            v.y = acc[i][q*4+1] + bv.y;
            v.z = acc[i][q*4+2] + bv.z;
            v.w = acc[i][q*4+3] + bv.w;
            if (MODE == 0) {
                *(float4*)&C[(size_t)row * Dn + col] = v;
            } else {
                const int s  = row & (Sn - 1);
                const int bb = row >> 11;           // Sn == 2048
                const int hh = col >> 6;
                const int dd = col & 63;
                *(float4*)&C[((((size_t)bb * Hn + hh) * Sn + s) << 6) + dd] = v;
            }
        }
    }
}

// ---------------------------------------------------------------------------
// Causal flash attention, fp32. One block = (b, h, 64-query tile).
// Q,K,V in [B,H,S,64]. Online softmax; PV via broadcast shuffles of P.
// ---------------------------------------------------------------------------
__global__ __launch_bounds__(256)
void attn_fwd(const float* __restrict__ Q, const float* __restrict__ Kp,
              const float* __restrict__ Vp, float* __restrict__ Z)
{
    __shared__ float Qs[64][64];  // [d][m]  (Q pre-scaled by 1/8)
    __shared__ float Ks[64][64];  // [d][n]
    __shared__ float Vs[64][64];  // [key][d]
    const int tid = threadIdx.x;
    const int tx = tid & 15, ty = tid >> 4;
    const int lane = tid & 63;
    const int lanebase = lane & 48;
    const int qb = (int)gridDim.x - 1 - (int)blockIdx.x;  // heavy blocks first
    const int h = blockIdx.y, b = blockIdx.z;
    const int q0 = qb << 6;
    const size_t hoff = ((size_t)(b * Hn + h) * Sn) * HDn;
    const float* Qh = Q  + hoff;
    const float* Kh = Kp + hoff;
    const float* Vh = Vp + hoff;

    // stage Q (scaled by 1/sqrt(64)), d-major
#pragma unroll
    for (int it = 0; it < 4; ++it) {
        const int v  = tid + (it << 8);
        const int rr = v >> 4, cc = (v & 15) << 2;
        const float4 qv = *(const float4*)&Qh[(size_t)(q0 + rr) * HDn + cc];
        Qs[cc+0][rr] = qv.x * 0.125f;
        Qs[cc+1][rr] = qv.y * 0.125f;
        Qs[cc+2][rr] = qv.z * 0.125f;
        Qs[cc+3][rr] = qv.w * 0.125f;
    }

    float acc[4][4];
#pragma unroll
    for (int i = 0; i < 4; ++i)
#pragma unroll
        for (int u = 0; u < 4; ++u) acc[i][u] = 0.f;
    float mrun[4], lrun[4];
#pragma unroll
    for (int i = 0; i < 4; ++i) { mrun[i] = -1e30f; lrun[i] = 0.f; }

    for (int t0 = 0; t0 <= q0; t0 += 64) {
        __syncthreads();   // prev tile compute done (also fences Q staging)
        // stage K (d-major) and V (row-major)
#pragma unroll
        for (int it = 0; it < 4; ++it) {
            const int v  = tid + (it << 8);
            const int rr = v >> 4, cc = (v & 15) << 2;
            const float4 kv = *(const float4*)&Kh[(size_t)(t0 + rr) * HDn + cc];
            Ks[cc+0][rr] = kv.x; Ks[cc+1][rr] = kv.y; Ks[cc+2][rr] = kv.z; Ks[cc+3][rr] = kv.w;
            const float4 vv = *(const float4*)&Vh[(size_t)(t0 + rr) * HDn + cc];
            *(float4*)&Vs[rr][cc] = vv;
        }
        __syncthreads();

        // QK^T tile: sc[i][j], rows ty*4+i, keys tx*4+j
        float sc[4][4];
#pragma unroll
        for (int i = 0; i < 4; ++i)
#pragma unroll
            for (int j = 0; j < 4; ++j) sc[i][j] = 0.f;
#pragma unroll
        for (int d = 0; d < 64; ++d) {
            const float4 av = *(const float4*)&Qs[d][ty << 2];
            const float4 bv = *(const float4*)&Ks[d][tx << 2];
            const float a[4] = {av.x, av.y, av.z, av.w};
            const float kk[4] = {bv.x, bv.y, bv.z, bv.w};
#pragma unroll
            for (int i = 0; i < 4; ++i)
#pragma unroll
                for (int j = 0; j < 4; ++j)
                    sc[i][j] += a[i] * kk[j];
        }
        if (t0 == q0) {   // diagonal tile: causal mask
#pragma unroll
            for (int i = 0; i < 4; ++i)
#pragma unroll
                for (int j = 0; j < 4; ++j)
                    if ((tx << 2) + j > (ty << 2) + i) sc[i][j] = -1e30f;
        }

        // online softmax (row stats across the 16 tx lanes)
        float p[4][4];
#pragma unroll
        for (int i = 0; i < 4; ++i) {
            float rm = fmaxf(fmaxf(sc[i][0], sc[i][1]), fmaxf(sc[i][2], sc[i][3]));
            rm = fmaxf(rm, __shfl_xor(rm, 1));
            rm = fmaxf(rm, __shfl_xor(rm, 2));
            rm = fmaxf(rm, __shfl_xor(rm, 4));
            rm = fmaxf(rm, __shfl_xor(rm, 8));
            const float mnew  = fmaxf(mrun[i], rm);
            const float alpha = __expf(mrun[i] - mnew);
            float rs = 0.f;
#pragma unroll
            for (int j = 0; j < 4; ++j) { p[i][j] = __expf(sc[i][j] - mnew); rs += p[i][j]; }
            rs += __shfl_xor(rs, 1);
            rs += __shfl_xor(rs, 2);
            rs += __shfl_xor(rs, 4);
            rs += __shfl_xor(rs, 8);
            lrun[i] = lrun[i] * alpha + rs;
            mrun[i] = mnew;
#pragma unroll
            for (int u = 0; u < 4; ++u) acc[i][u] *= alpha;
        }

        // PV: acc[i][u] += sum_j P[row i][j] * Vs[j][tx*4+u]
#pragma unroll
        for (int j4 = 0; j4 < 16; ++j4) {
#pragma unroll
            for (int jj = 0; jj < 4; ++jj) {
                const int j = (j4 << 2) + jj;
                const float4 bv = *(const float4*)&Vs[j][tx << 2];
                const float p0 = __shfl(p[0][jj], lanebase + j4);
                const float p1 = __shfl(p[1][jj], lanebase + j4);
                const float p2 = __shfl(p[2][jj], lanebase + j4);
                const float p3 = __shfl(p[3][jj], lanebase + j4);
                acc[0][0] += p0 * bv.x; acc[0][1] += p0 * bv.y; acc[0][2] += p0 * bv.z; acc[0][3] += p0 * bv.w;
                acc[1][0] += p1 * bv.x; acc[1][1] += p1 * bv.y; acc[1][2] += p1 * bv.z; acc[1][3] += p1 * bv.w;
                acc[2][0] += p2 * bv.x; acc[2][1] += p2 * bv.y; acc[2][2] += p2 * bv.z; acc[2][3] += p2 * bv.w;
                acc[3][0] += p3 * bv.x; acc[3][1] += p3 * bv.y; acc[3][2] += p3 * bv.z; acc[3][3] += p3 * bv.w;
            }
        }
    }

    // epilogue: Z in [b, s, h, d] => flat [m][n] with n = h*64+d
#pragma unroll
    for (int i = 0; i < 4; ++i) {
        const float inv = 1.f / lrun[i];
        float4 o;
        o.x = acc[i][0] * inv; o.y = acc[i][1] * inv;
        o.z = acc[i][2] * inv; o.w = acc[i][3] * inv;
        *(float4*)&Z[(((size_t)(b * Sn + q0 + (ty << 2) + i) * Hn + h) << 6) + (tx << 2)] = o;
    }
}

// ---------------------------------------------------------------------------
extern "C" void kernel_launch(void* const* d_in, const int* in_sizes, int n_in,
                              void* d_out, int out_size, void* d_ws, size_t ws_size,
                              hipStream_t stream)
{
    const float* x  = (const float*)d_in[0];
    // d_in[1] = causal mask (bool) — implemented analytically, not read
    const float* Wq = (const float*)d_in[2];
    const float* bq = (const float*)d_in[3];
    const float* Wk = (const float*)d_in[4];
    const float* bk = (const float*)d_in[5];
    const float* Wv = (const float*)d_in[6];
    const float* bv = (const float*)d_in[7];
    const float* Wo = (const float*)d_in[8];
    const float* bo = (const float*)d_in[9];
    float* out = (float*)d_out;

    const size_t NBUF = (size_t)MROWS * Dn;   // 8388608 floats per buffer
    float* Qb = (float*)d_ws;
    float* Kb = Qb + NBUF;
    float* Vb = Kb + NBUF;
    float* Zb = Vb + NBUF;

    const dim3 gproj(Dn / 128, MROWS / 128);  // (8, 64)
    gemm_nt<1><<<gproj, 256, 0, stream>>>(x, Wq, bq, Qb);
    gemm_nt<1><<<gproj, 256, 0, stream>>>(x, Wk, bk, Kb);
    gemm_nt<1><<<gproj, 256, 0, stream>>>(x, Wv, bv, Vb);

    attn_fwd<<<dim3(Sn / 64, Hn, Bn), 256, 0, stream>>>(Qb, Kb, Vb, Zb);

    gemm_nt<0><<<gproj, 256, 0, stream>>>(Zb, Wo, bo, out);
}

// Round 2
// 1393.212 us; speedup vs baseline: 1.6972x; 1.6972x over previous
//
#include <hip/hip_runtime.h>

#define Bn 4
#define Sn 2048
#define Dn 1024
#define Hn 16
#define HDn 64
#define MROWS (Bn * Sn)   // 8192

typedef __attribute__((ext_vector_type(4))) float f32x4;
typedef __attribute__((ext_vector_type(8))) short s16x8;

__device__ inline short f2bf(float x) {
    unsigned u = __float_as_uint(x);
    unsigned r = (u + 0x7FFFu + ((u >> 16) & 1u)) >> 16;
    return (short)r;
}
__device__ inline float bf2f(short h) {
    return __uint_as_float(((unsigned)(unsigned short)h) << 16);
}

// ---------------------------------------------------------------------------
// NT GEMM: C[m][n] = sum_k A[m][k] * W[n][k] + bias[n]   (fp32, unchanged)
// MODE 0: C[m*Dn + n]; MODE 1: head-interleaved [B,H,S,64]
// ---------------------------------------------------------------------------
template<int MODE>
__global__ __launch_bounds__(256)
void gemm_nt(const float* __restrict__ A, const float* __restrict__ W,
             const float* __restrict__ bias, float* __restrict__ C)
{
    __shared__ float As[16][128];
    __shared__ float Bs[16][128];
    const int tid = threadIdx.x;
    const int tx = tid & 15, ty = tid >> 4;
    const int n0 = blockIdx.x * 128;
    const int m0 = blockIdx.y * 128;
    const int r  = tid >> 2;
    const int c4 = (tid & 3) << 2;
    const int K  = Dn;

    float acc[8][8];
#pragma unroll
    for (int i = 0; i < 8; ++i)
#pragma unroll
        for (int j = 0; j < 8; ++j) acc[i][j] = 0.f;

    const float* Arow0 = A + (size_t)(m0 + r) * K + c4;
    const float* Arow1 = A + (size_t)(m0 + 64 + r) * K + c4;
    const float* Wrow0 = W + (size_t)(n0 + r) * K + c4;
    const float* Wrow1 = W + (size_t)(n0 + 64 + r) * K + c4;

    for (int k0 = 0; k0 < K; k0 += 16) {
        const float4 a0 = *(const float4*)(Arow0 + k0);
        const float4 a1 = *(const float4*)(Arow1 + k0);
        const float4 w0 = *(const float4*)(Wrow0 + k0);
        const float4 w1 = *(const float4*)(Wrow1 + k0);
        __syncthreads();
        As[c4+0][r]    = a0.x; As[c4+1][r]    = a0.y; As[c4+2][r]    = a0.z; As[c4+3][r]    = a0.w;
        As[c4+0][64+r] = a1.x; As[c4+1][64+r] = a1.y; As[c4+2][64+r] = a1.z; As[c4+3][64+r] = a1.w;
        Bs[c4+0][r]    = w0.x; Bs[c4+1][r]    = w0.y; Bs[c4+2][r]    = w0.z; Bs[c4+3][r]    = w0.w;
        Bs[c4+0][64+r] = w1.x; Bs[c4+1][64+r] = w1.y; Bs[c4+2][64+r] = w1.z; Bs[c4+3][64+r] = w1.w;
        __syncthreads();
#pragma unroll
        for (int k = 0; k < 16; ++k) {
            const float4 av0 = *(const float4*)&As[k][ty << 2];
            const float4 av1 = *(const float4*)&As[k][64 + (ty << 2)];
            const float4 bv0 = *(const float4*)&Bs[k][tx << 2];
            const float4 bv1 = *(const float4*)&Bs[k][64 + (tx << 2)];
            const float a[8] = {av0.x, av0.y, av0.z, av0.w, av1.x, av1.y, av1.z, av1.w};
            const float b[8] = {bv0.x, bv0.y, bv0.z, bv0.w, bv1.x, bv1.y, bv1.z, bv1.w};
#pragma unroll
            for (int i = 0; i < 8; ++i)
#pragma unroll
                for (int j = 0; j < 8; ++j)
                    acc[i][j] += a[i] * b[j];
        }
    }

#pragma unroll
    for (int i = 0; i < 8; ++i) {
        const int row = m0 + ((i & 4) << 4) + (ty << 2) + (i & 3);
#pragma unroll
        for (int q = 0; q < 2; ++q) {
            const int col = n0 + q * 64 + (tx << 2);
            const float4 bv = *(const float4*)&bias[col];
            float4 v;
            v.x = acc[i][q*4+0] + bv.x;
            v.y = acc[i][q*4+1] + bv.y;
            v.z = acc[i][q*4+2] + bv.z;
            v.w = acc[i][q*4+3] + bv.w;
            if (MODE == 0) {
                *(float4*)&C[(size_t)row * Dn + col] = v;
            } else {
                const int s  = row & (Sn - 1);
                const int bb = row >> 11;
                const int hh = col >> 6;
                const int dd = col & 63;
                *(float4*)&C[((((size_t)bb * Hn + hh) * Sn + s) << 6) + dd] = v;
            }
        }
    }
}

// ---------------------------------------------------------------------------
// Causal flash attention with split-bf16 MFMA.
// Block = (b, h, 64-query tile), 4 waves x 16 queries.
// QK^T: 3-term split (QhiKhi + QhiKlo + QloKhi) -> ~fp32 accuracy.
// PV:   P plain bf16 (P in [0,1]), V split hi/lo (2 MFMAs).
// LDS rows padded to 72 shorts (144B) -> conflict-light, 16B-aligned frags.
// ---------------------------------------------------------------------------
__global__ __launch_bounds__(256)
void attn_fwd(const float* __restrict__ Q, const float* __restrict__ Kp,
              const float* __restrict__ Vp, float* __restrict__ Z)
{
    __shared__ __align__(16) short KsHi[64 * 72];   // [key][d]
    __shared__ __align__(16) short KsLo[64 * 72];
    __shared__ __align__(16) short VsHi[64 * 72];   // [d][key] (transposed)
    __shared__ __align__(16) short VsLo[64 * 72];
    __shared__ __align__(16) short Ps[4 * 16 * 72]; // per-wave P: [q][key]

    const int tid  = threadIdx.x;
    const int lane = tid & 63;
    const int w    = tid >> 6;       // wave 0..3
    const int l15  = lane & 15;
    const int lg   = lane >> 4;      // 0..3
    const int qb = (int)gridDim.x - 1 - (int)blockIdx.x;  // heavy blocks first
    const int h = blockIdx.y, b = blockIdx.z;
    const int q0 = qb << 6;
    const size_t hoff = ((size_t)(b * Hn + h) * Sn) * HDn;
    const float* Qh = Q  + hoff;
    const float* Kh = Kp + hoff;
    const float* Vh = Vp + hoff;

    // Q A-fragments (pre-scaled by 1/8): row q = q0 + w*16 + l15,
    // k-dim d = ks*32 + lg*8 + j
    s16x8 qhi[2], qlo[2];
#pragma unroll
    for (int ks = 0; ks < 2; ++ks) {
        const float* src = &Qh[(size_t)(q0 + w * 16 + l15) * HDn + ks * 32 + lg * 8];
        const float4 x0 = *(const float4*)src;
        const float4 x1 = *(const float4*)(src + 4);
        const float xs[8] = {x0.x, x0.y, x0.z, x0.w, x1.x, x1.y, x1.z, x1.w};
#pragma unroll
        for (int j = 0; j < 8; ++j) {
            const float v = xs[j] * 0.125f;
            const short hi = f2bf(v);
            qhi[ks][j] = hi;
            qlo[ks][j] = f2bf(v - bf2f(hi));
        }
    }

    f32x4 acc[4];                   // Z acc: d-group nt, rows (lg*4+r), col l15
#pragma unroll
    for (int nt = 0; nt < 4; ++nt) acc[nt] = (f32x4){0.f, 0.f, 0.f, 0.f};
    float mrun[4], lrun[4];
#pragma unroll
    for (int r = 0; r < 4; ++r) { mrun[r] = -1e30f; lrun[r] = 0.f; }

    short* Pw = &Ps[w * 16 * 72];

    for (int t0 = 0; t0 <= q0; t0 += 64) {
        __syncthreads();   // all waves done reading previous K/V tile
        // ---- stage K (hi/lo, [k][d]) and V (hi/lo, transposed [d][k]) ----
#pragma unroll
        for (int it = 0; it < 4; ++it) {
            const int idx = tid + (it << 8);
            const int rr = idx >> 4;             // key row 0..63
            const int cc = (idx & 15) << 2;      // d col 0,4,..,60
            const float4 kv = *(const float4*)&Kh[(size_t)(t0 + rr) * HDn + cc];
            const float4 vv = *(const float4*)&Vh[(size_t)(t0 + rr) * HDn + cc];
            const float ka[4] = {kv.x, kv.y, kv.z, kv.w};
            const float va[4] = {vv.x, vv.y, vv.z, vv.w};
            short kh4[4], kl4[4];
#pragma unroll
            for (int i = 0; i < 4; ++i) {
                const short khi = f2bf(ka[i]);
                kh4[i] = khi;
                kl4[i] = f2bf(ka[i] - bf2f(khi));
                const short vhi = f2bf(va[i]);
                VsHi[(cc + i) * 72 + rr] = vhi;
                VsLo[(cc + i) * 72 + rr] = f2bf(va[i] - bf2f(vhi));
            }
            *(short4*)&KsHi[rr * 72 + cc] = make_short4(kh4[0], kh4[1], kh4[2], kh4[3]);
            *(short4*)&KsLo[rr * 72 + cc] = make_short4(kl4[0], kl4[1], kl4[2], kl4[3]);
        }
        __syncthreads();

        // ---- S = Q K^T (16q x 64k per wave), split-bf16 ----
        f32x4 s[4];
#pragma unroll
        for (int nt = 0; nt < 4; ++nt) {
            f32x4 sv = (f32x4){0.f, 0.f, 0.f, 0.f};
            const int krow = nt * 16 + l15;
#pragma unroll
            for (int ks = 0; ks < 2; ++ks) {
                const s16x8 kh = *(const s16x8*)&KsHi[krow * 72 + ks * 32 + lg * 8];
                const s16x8 kl = *(const s16x8*)&KsLo[krow * 72 + ks * 32 + lg * 8];
                sv = __builtin_amdgcn_mfma_f32_16x16x32_bf16(qhi[ks], kh, sv, 0, 0, 0);
                sv = __builtin_amdgcn_mfma_f32_16x16x32_bf16(qhi[ks], kl, sv, 0, 0, 0);
                sv = __builtin_amdgcn_mfma_f32_16x16x32_bf16(qlo[ks], kh, sv, 0, 0, 0);
            }
            s[nt] = sv;
        }

        // ---- causal mask on diagonal tile ----
        if (t0 == q0) {
#pragma unroll
            for (int nt = 0; nt < 4; ++nt) {
                const int kk = nt * 16 + l15;          // key within block tile
#pragma unroll
                for (int r = 0; r < 4; ++r) {
                    const int qq = w * 16 + lg * 4 + r; // query within block tile
                    if (kk > qq) s[nt][r] = -1e30f;
                }
            }
        }

        // ---- online softmax (fp32), rows r, reduce across 16 k-lanes ----
#pragma unroll
        for (int r = 0; r < 4; ++r) {
            float rm = fmaxf(fmaxf(s[0][r], s[1][r]), fmaxf(s[2][r], s[3][r]));
            rm = fmaxf(rm, __shfl_xor(rm, 1));
            rm = fmaxf(rm, __shfl_xor(rm, 2));
            rm = fmaxf(rm, __shfl_xor(rm, 4));
            rm = fmaxf(rm, __shfl_xor(rm, 8));
            const float mnew  = fmaxf(mrun[r], rm);
            const float alpha = __expf(mrun[r] - mnew);
            mrun[r] = mnew;
            float rs = 0.f;
#pragma unroll
            for (int nt = 0; nt < 4; ++nt) {
                const float p = __expf(s[nt][r] - mnew);
                s[nt][r] = p;
                rs += p;
            }
            rs += __shfl_xor(rs, 1);
            rs += __shfl_xor(rs, 2);
            rs += __shfl_xor(rs, 4);
            rs += __shfl_xor(rs, 8);
            lrun[r] = lrun[r] * alpha + rs;
#pragma unroll
            for (int nt = 0; nt < 4; ++nt) acc[nt][r] *= alpha;
        }

        // ---- P -> LDS (bf16), re-layout for PV A-fragments ----
#pragma unroll
        for (int nt = 0; nt < 4; ++nt)
#pragma unroll
            for (int r = 0; r < 4; ++r)
                Pw[(lg * 4 + r) * 72 + nt * 16 + l15] = f2bf(s[nt][r]);

        // ---- Z += P V  (V split hi/lo) ----
        const s16x8 pa0 = *(const s16x8*)&Pw[l15 * 72 + lg * 8];
        const s16x8 pa1 = *(const s16x8*)&Pw[l15 * 72 + 32 + lg * 8];
#pragma unroll
        for (int nt = 0; nt < 4; ++nt) {
            const int dr = nt * 16 + l15;
            const s16x8 vh0 = *(const s16x8*)&VsHi[dr * 72 + lg * 8];
            const s16x8 vl0 = *(const s16x8*)&VsLo[dr * 72 + lg * 8];
            const s16x8 vh1 = *(const s16x8*)&VsHi[dr * 72 + 32 + lg * 8];
            const s16x8 vl1 = *(const s16x8*)&VsLo[dr * 72 + 32 + lg * 8];
            acc[nt] = __builtin_amdgcn_mfma_f32_16x16x32_bf16(pa0, vh0, acc[nt], 0, 0, 0);
            acc[nt] = __builtin_amdgcn_mfma_f32_16x16x32_bf16(pa0, vl0, acc[nt], 0, 0, 0);
            acc[nt] = __builtin_amdgcn_mfma_f32_16x16x32_bf16(pa1, vh1, acc[nt], 0, 0, 0);
            acc[nt] = __builtin_amdgcn_mfma_f32_16x16x32_bf16(pa1, vl1, acc[nt], 0, 0, 0);
        }
    }

    // ---- epilogue: Z[b,s,h,d], divide by l ----
#pragma unroll
    for (int r = 0; r < 4; ++r) {
        const float inv = 1.f / lrun[r];
        const int qq = q0 + w * 16 + lg * 4 + r;
        float* dst = &Z[(size_t)(b * Sn + qq) * Dn + h * HDn];
#pragma unroll
        for (int nt = 0; nt < 4; ++nt)
            dst[nt * 16 + l15] = acc[nt][r] * inv;
    }
}

// ---------------------------------------------------------------------------
extern "C" void kernel_launch(void* const* d_in, const int* in_sizes, int n_in,
                              void* d_out, int out_size, void* d_ws, size_t ws_size,
                              hipStream_t stream)
{
    const float* x  = (const float*)d_in[0];
    // d_in[1] = causal mask (bool) — implemented analytically, not read
    const float* Wq = (const float*)d_in[2];
    const float* bq = (const float*)d_in[3];
    const float* Wk = (const float*)d_in[4];
    const float* bk = (const float*)d_in[5];
    const float* Wv = (const float*)d_in[6];
    const float* bv = (const float*)d_in[7];
    const float* Wo = (const float*)d_in[8];
    const float* bo = (const float*)d_in[9];
    float* out = (float*)d_out;

    const size_t NBUF = (size_t)MROWS * Dn;
    float* Qb = (float*)d_ws;
    float* Kb = Qb + NBUF;
    float* Vb = Kb + NBUF;
    float* Zb = Vb + NBUF;

    const dim3 gproj(Dn / 128, MROWS / 128);  // (8, 64)
    gemm_nt<1><<<gproj, 256, 0, stream>>>(x, Wq, bq, Qb);
    gemm_nt<1><<<gproj, 256, 0, stream>>>(x, Wk, bk, Kb);
    gemm_nt<1><<<gproj, 256, 0, stream>>>(x, Wv, bv, Vb);

    attn_fwd<<<dim3(Sn / 64, Hn, Bn), 256, 0, stream>>>(Qb, Kb, Vb, Zb);

    gemm_nt<0><<<gproj, 256, 0, stream>>>(Zb, Wo, bo, out);
}

// Round 3
// 768.286 us; speedup vs baseline: 3.0778x; 1.8134x over previous
//
#include <hip/hip_runtime.h>

#define Bn 4
#define Sn 2048
#define Dn 1024
#define Hn 16
#define HDn 64
#define MROWS (Bn * Sn)   // 8192

typedef __attribute__((ext_vector_type(4))) float f32x4;
typedef __attribute__((ext_vector_type(8))) short s16x8;
typedef unsigned int u32;

__device__ inline short f2bf(float x) {
    unsigned u = __float_as_uint(x);
    unsigned r = (u + 0x7FFFu + ((u >> 16) & 1u)) >> 16;
    return (short)r;
}
__device__ inline float bf2f(short h) {
    return __uint_as_float(((unsigned)(unsigned short)h) << 16);
}
__device__ inline void gld_lds16(const void* g, void* l) {
    __builtin_amdgcn_global_load_lds(
        (const __attribute__((address_space(1))) u32*)g,
        (__attribute__((address_space(3))) u32*)l, 16, 0, 0);
}

// ---------------------------------------------------------------------------
// split fp32 -> (hi, lo) bf16 planes
// ---------------------------------------------------------------------------
__global__ __launch_bounds__(256)
void split_planes(const float* __restrict__ in, short* __restrict__ hi,
                  short* __restrict__ lo, int n4)
{
    const int i = blockIdx.x * 256 + threadIdx.x;
    if (i >= n4) return;
    const float4 v = ((const float4*)in)[i];
    short4 h, l;
    h.x = f2bf(v.x); l.x = f2bf(v.x - bf2f(h.x));
    h.y = f2bf(v.y); l.y = f2bf(v.y - bf2f(h.y));
    h.z = f2bf(v.z); l.z = f2bf(v.z - bf2f(h.z));
    h.w = f2bf(v.w); l.w = f2bf(v.w - bf2f(h.w));
    ((short4*)hi)[i] = h;
    ((short4*)lo)[i] = l;
}

__global__ __launch_bounds__(256)
void copy_f32(const float* __restrict__ in, float* __restrict__ out, int n4)
{
    const int i = blockIdx.x * 256 + threadIdx.x;
    if (i < n4) ((float4*)out)[i] = ((const float4*)in)[i];
}

// ---------------------------------------------------------------------------
// Split-bf16 NT GEMM: C[m][n] = sum_k A[m][k] * W[n][k] + bias[n]
// A fp32 (reg-staged + split in-loop), W as pre-split hi/lo planes (gld_lds).
// 3-term: AhiBhi + AhiBlo + AloBhi  (~fp32 accuracy).
// MODE 0: fp32 C[m][Dn]   (final projection)
// MODE 1: fp32 Q [b,h,s,d] scaled by 0.125
// MODE 2: K hi/lo planes [b,h,s,d]
// MODE 3: V hi/lo planes [b,h,d,s] (transposed)
// ---------------------------------------------------------------------------
template<int MODE>
__global__ __launch_bounds__(256)
void gemm_split(const float* __restrict__ A, const short* __restrict__ Bhip,
                const short* __restrict__ Blop, const float* __restrict__ bias,
                float* __restrict__ Cf, short* __restrict__ Chi,
                short* __restrict__ Clo)
{
    __shared__ __align__(16) short Ah[128 * 32];
    __shared__ __align__(16) short Al[128 * 32];
    __shared__ __align__(16) short Bh[128 * 32];
    __shared__ __align__(16) short Bl[128 * 32];
    const int tid = threadIdx.x;
    const int lane = tid & 63;
    const int w = tid >> 6;
    const int l15 = lane & 15, lg = lane >> 4;
    const int wr = w >> 1, wc = w & 1;
    const int n0 = blockIdx.x * 128, m0 = blockIdx.y * 128;

    f32x4 acc[4][4];
#pragma unroll
    for (int mi = 0; mi < 4; ++mi)
#pragma unroll
        for (int ni = 0; ni < 4; ++ni) acc[mi][ni] = (f32x4){0.f, 0.f, 0.f, 0.f};

    // B-plane gld_lds lane constants: row = rb + (lane>>2), lds chunk = lane&3,
    // source chunk = (lane&3) ^ swz(row), swz(row) = (row&3)^((row>>2)&3)
    const int brsub = lane >> 2;
    const int bch = (lane & 3) ^ ((lane >> 2) & 3) ^ ((lane >> 4) & 3);
    const int fsw = (l15 & 3) ^ ((l15 >> 2) & 3);   // fragment-read swizzle

    for (int k0 = 0; k0 < Dn; k0 += 32) {
        __syncthreads();
        // ---- stage B planes via global_load_lds (16B/lane, linear dest) ----
#pragma unroll
        for (int c = 0; c < 2; ++c) {
            const int rb = (w * 2 + c) * 16;
            const size_t gsrc = (size_t)(n0 + rb + brsub) * Dn + k0 + bch * 8;
            gld_lds16(Bhip + gsrc, &Bh[rb * 32]);
            gld_lds16(Blop + gsrc, &Bl[rb * 32]);
        }
        // ---- stage A: fp32 load, split, swizzled ds_write ----
#pragma unroll
        for (int it = 0; it < 4; ++it) {
            const int qi = tid + (it << 8);
            const int row = qi >> 3, qc = qi & 7;
            const float4 v = *(const float4*)&A[(size_t)(m0 + row) * Dn + k0 + qc * 4];
            short4 h4, l4;
            h4.x = f2bf(v.x); l4.x = f2bf(v.x - bf2f(h4.x));
            h4.y = f2bf(v.y); l4.y = f2bf(v.y - bf2f(h4.y));
            h4.z = f2bf(v.z); l4.z = f2bf(v.z - bf2f(h4.z));
            h4.w = f2bf(v.w); l4.w = f2bf(v.w - bf2f(h4.w));
            const int sw = (qc >> 1) ^ (row & 3) ^ ((row >> 2) & 3);
            const int off = row * 32 + sw * 8 + (qc & 1) * 4;
            *(short4*)&Ah[off] = h4;
            *(short4*)&Al[off] = l4;
        }
        __syncthreads();

        // ---- fragments + MFMA ----
        s16x8 ah[4], al[4];
#pragma unroll
        for (int mi = 0; mi < 4; ++mi) {
            const int ar = wr * 64 + mi * 16 + l15;
            const int off = ar * 32 + ((lg ^ fsw) << 3);
            ah[mi] = *(const s16x8*)&Ah[off];
            al[mi] = *(const s16x8*)&Al[off];
        }
#pragma unroll
        for (int ni = 0; ni < 4; ++ni) {
            const int br = wc * 64 + ni * 16 + l15;
            const int off = br * 32 + ((lg ^ fsw) << 3);
            const s16x8 bh = *(const s16x8*)&Bh[off];
            const s16x8 bl = *(const s16x8*)&Bl[off];
#pragma unroll
            for (int mi = 0; mi < 4; ++mi) {
                acc[mi][ni] = __builtin_amdgcn_mfma_f32_16x16x32_bf16(ah[mi], bh, acc[mi][ni], 0, 0, 0);
                acc[mi][ni] = __builtin_amdgcn_mfma_f32_16x16x32_bf16(ah[mi], bl, acc[mi][ni], 0, 0, 0);
                acc[mi][ni] = __builtin_amdgcn_mfma_f32_16x16x32_bf16(al[mi], bh, acc[mi][ni], 0, 0, 0);
            }
        }
    }

    // ---- epilogue ----
#pragma unroll
    for (int ni = 0; ni < 4; ++ni) {
        const int col = n0 + wc * 64 + ni * 16 + l15;
        const float bcol = bias[col];
        const int hh = col >> 6, dd = col & 63;
#pragma unroll
        for (int mi = 0; mi < 4; ++mi) {
            const int mb = m0 + wr * 64 + mi * 16 + (lg << 2);
            const int ss = mb & (Sn - 1);
            const int bb = mb >> 11;
            if (MODE == 0) {
#pragma unroll
                for (int r = 0; r < 4; ++r)
                    Cf[(size_t)(mb + r) * Dn + col] = acc[mi][ni][r] + bcol;
            } else if (MODE == 1) {
#pragma unroll
                for (int r = 0; r < 4; ++r)
                    Cf[((((size_t)bb * Hn + hh) * Sn + (ss + r)) << 6) + dd] =
                        (acc[mi][ni][r] + bcol) * 0.125f;
            } else if (MODE == 2) {
#pragma unroll
                for (int r = 0; r < 4; ++r) {
                    const float v = acc[mi][ni][r] + bcol;
                    const short hv = f2bf(v);
                    const size_t ad = ((((size_t)bb * Hn + hh) * Sn + (ss + r)) << 6) + dd;
                    Chi[ad] = hv;
                    Clo[ad] = f2bf(v - bf2f(hv));
                }
            } else {
                float vr[4];
                short4 hv, lv;
                vr[0] = acc[mi][ni][0] + bcol; vr[1] = acc[mi][ni][1] + bcol;
                vr[2] = acc[mi][ni][2] + bcol; vr[3] = acc[mi][ni][3] + bcol;
                hv.x = f2bf(vr[0]); lv.x = f2bf(vr[0] - bf2f(hv.x));
                hv.y = f2bf(vr[1]); lv.y = f2bf(vr[1] - bf2f(hv.y));
                hv.z = f2bf(vr[2]); lv.z = f2bf(vr[2] - bf2f(hv.z));
                hv.w = f2bf(vr[3]); lv.w = f2bf(vr[3] - bf2f(hv.w));
                const size_t ad = (((size_t)bb * Hn + hh) * HDn + dd) * Sn + ss;
                *(short4*)&Chi[ad] = hv;
                *(short4*)&Clo[ad] = lv;
            }
        }
    }
}

// ---------------------------------------------------------------------------
// Causal flash attention, split-bf16 MFMA, bf16-plane inputs.
// Block = (b, h, 128-query tile), 4 waves x 32 queries; K/V tiles of 64 keys.
// Q fp32 (pre-scaled); K planes [b,h,s,d]; V^T planes [b,h,d,s]; Z fp32 out.
// ---------------------------------------------------------------------------
__global__ __launch_bounds__(256)
void attn_fwd(const float* __restrict__ Qf, const short* __restrict__ Khi,
              const short* __restrict__ Klo, const short* __restrict__ Vhi,
              const short* __restrict__ Vlo, float* __restrict__ Z)
{
    __shared__ __align__(16) short KsHi[64 * 64];
    __shared__ __align__(16) short KsLo[64 * 64];
    __shared__ __align__(16) short VsHi[64 * 64];   // [d][key]
    __shared__ __align__(16) short VsLo[64 * 64];
    __shared__ __align__(16) short Ps[4 * 32 * 72];

    const int tid = threadIdx.x, lane = tid & 63, w = tid >> 6;
    const int l15 = lane & 15, lg = lane >> 4;
    const int qb = (int)gridDim.x - 1 - (int)blockIdx.x;   // heavy blocks first
    const int h = blockIdx.y, b = blockIdx.z;
    const int q0b = qb << 7;
    const size_t khoff = ((size_t)(b * Hn + h) * Sn) * HDn;   // [b,h,s,d]
    const size_t vhoff = ((size_t)(b * Hn + h) * HDn) * Sn;   // [b,h,d,s]
    const short* Khg = Khi + khoff;
    const short* Klg = Klo + khoff;
    const short* Vhg = Vhi + vhoff;
    const short* Vlg = Vlo + vhoff;

    // ---- Q fragments (fp32 -> hi/lo), rows w*32 + miq*16 + l15 ----
    s16x8 qhi[2][2], qlo[2][2];
#pragma unroll
    for (int miq = 0; miq < 2; ++miq)
#pragma unroll
        for (int ks = 0; ks < 2; ++ks) {
            const float* src = &Qf[khoff + (size_t)(q0b + w * 32 + miq * 16 + l15) * HDn + ks * 32 + lg * 8];
            const float4 x0 = *(const float4*)src;
            const float4 x1 = *(const float4*)(src + 4);
            const float xs[8] = {x0.x, x0.y, x0.z, x0.w, x1.x, x1.y, x1.z, x1.w};
#pragma unroll
            for (int j = 0; j < 8; ++j) {
                const short hi = f2bf(xs[j]);
                qhi[miq][ks][j] = hi;
                qlo[miq][ks][j] = f2bf(xs[j] - bf2f(hi));
            }
        }

    f32x4 acc[2][4];
#pragma unroll
    for (int miq = 0; miq < 2; ++miq)
#pragma unroll
        for (int nt = 0; nt < 4; ++nt) acc[miq][nt] = (f32x4){0.f, 0.f, 0.f, 0.f};
    float mrun[2][4], lrun[2][4];
#pragma unroll
    for (int miq = 0; miq < 2; ++miq)
#pragma unroll
        for (int r = 0; r < 4; ++r) { mrun[miq][r] = -1e30f; lrun[miq][r] = 0.f; }

    short* Pw = &Ps[w * 32 * 72];
    const int srow = lane >> 3;                 // staging row-sub 0..7
    const int sch = (lane & 7) ^ srow;          // pre-swizzled source chunk
    const int qlo_w = q0b + w * 32;
    const int fsx = l15 & 7;                    // fragment-read swizzle

    for (int t0 = 0; t0 <= q0b + 64; t0 += 64) {
        __syncthreads();
        // ---- stage K and V^T planes (pure copies, swizzled source) ----
#pragma unroll
        for (int c = 0; c < 2; ++c) {
            const int rb = (w * 2 + c) * 8;
            const size_t ksrc = (size_t)(t0 + rb + srow) * HDn + sch * 8;
            gld_lds16(Khg + ksrc, &KsHi[rb * 64]);
            gld_lds16(Klg + ksrc, &KsLo[rb * 64]);
            const size_t vsrc = (size_t)(rb + srow) * Sn + t0 + sch * 8;
            gld_lds16(Vhg + vsrc, &VsHi[rb * 64]);
            gld_lds16(Vlg + vsrc, &VsLo[rb * 64]);
        }
        __syncthreads();

        const bool need_mask = (t0 >= q0b);

        // ---- S = Q K^T ----
        f32x4 sv[2][4];
#pragma unroll
        for (int nt = 0; nt < 4; ++nt) {
            const int krow = nt * 16 + l15;
            const s16x8 kh0 = *(const s16x8*)&KsHi[krow * 64 + ((lg ^ fsx) << 3)];
            const s16x8 kl0 = *(const s16x8*)&KsLo[krow * 64 + ((lg ^ fsx) << 3)];
            const s16x8 kh1 = *(const s16x8*)&KsHi[krow * 64 + (((4 + lg) ^ fsx) << 3)];
            const s16x8 kl1 = *(const s16x8*)&KsLo[krow * 64 + (((4 + lg) ^ fsx) << 3)];
#pragma unroll
            for (int miq = 0; miq < 2; ++miq) {
                if (t0 > qlo_w + miq * 16 + 15) continue;
                f32x4 s = (f32x4){0.f, 0.f, 0.f, 0.f};
                s = __builtin_amdgcn_mfma_f32_16x16x32_bf16(qhi[miq][0], kh0, s, 0, 0, 0);
                s = __builtin_amdgcn_mfma_f32_16x16x32_bf16(qhi[miq][0], kl0, s, 0, 0, 0);
                s = __builtin_amdgcn_mfma_f32_16x16x32_bf16(qlo[miq][0], kh0, s, 0, 0, 0);
                s = __builtin_amdgcn_mfma_f32_16x16x32_bf16(qhi[miq][1], kh1, s, 0, 0, 0);
                s = __builtin_amdgcn_mfma_f32_16x16x32_bf16(qhi[miq][1], kl1, s, 0, 0, 0);
                s = __builtin_amdgcn_mfma_f32_16x16x32_bf16(qlo[miq][1], kh1, s, 0, 0, 0);
                sv[miq][nt] = s;
            }
        }

        // ---- mask + online softmax + P write ----
#pragma unroll
        for (int miq = 0; miq < 2; ++miq) {
            if (t0 > qlo_w + miq * 16 + 15) continue;
            if (need_mask) {
#pragma unroll
                for (int nt = 0; nt < 4; ++nt) {
                    const int key = t0 + nt * 16 + l15;
#pragma unroll
                    for (int r = 0; r < 4; ++r) {
                        const int qg = qlo_w + miq * 16 + (lg << 2) + r;
                        if (key > qg) sv[miq][nt][r] = -1e30f;
                    }
                }
            }
#pragma unroll
            for (int r = 0; r < 4; ++r) {
                float rm = fmaxf(fmaxf(sv[miq][0][r], sv[miq][1][r]),
                                 fmaxf(sv[miq][2][r], sv[miq][3][r]));
                rm = fmaxf(rm, __shfl_xor(rm, 1));
                rm = fmaxf(rm, __shfl_xor(rm, 2));
                rm = fmaxf(rm, __shfl_xor(rm, 4));
                rm = fmaxf(rm, __shfl_xor(rm, 8));
                const float mnew  = fmaxf(mrun[miq][r], rm);
                const float alpha = __expf(mrun[miq][r] - mnew);
                mrun[miq][r] = mnew;
                float rs = 0.f;
#pragma unroll
                for (int nt = 0; nt < 4; ++nt) {
                    const float p = __expf(sv[miq][nt][r] - mnew);
                    sv[miq][nt][r] = p;
                    rs += p;
                }
                rs += __shfl_xor(rs, 1);
                rs += __shfl_xor(rs, 2);
                rs += __shfl_xor(rs, 4);
                rs += __shfl_xor(rs, 8);
                lrun[miq][r] = lrun[miq][r] * alpha + rs;
#pragma unroll
                for (int nt = 0; nt < 4; ++nt) acc[miq][nt][r] *= alpha;
            }
#pragma unroll
            for (int nt = 0; nt < 4; ++nt)
#pragma unroll
                for (int r = 0; r < 4; ++r)
                    Pw[(miq * 16 + (lg << 2) + r) * 72 + nt * 16 + l15] = f2bf(sv[miq][nt][r]);
        }

        // ---- Z += P V ----
        s16x8 pa[2][2];
#pragma unroll
        for (int miq = 0; miq < 2; ++miq)
            if (t0 <= qlo_w + miq * 16 + 15) {
                pa[miq][0] = *(const s16x8*)&Pw[(miq * 16 + l15) * 72 + (lg << 3)];
                pa[miq][1] = *(const s16x8*)&Pw[(miq * 16 + l15) * 72 + 32 + (lg << 3)];
            }
#pragma unroll
        for (int nt = 0; nt < 4; ++nt) {
            const int drow = nt * 16 + l15;
            const s16x8 vh0 = *(const s16x8*)&VsHi[drow * 64 + ((lg ^ fsx) << 3)];
            const s16x8 vl0 = *(const s16x8*)&VsLo[drow * 64 + ((lg ^ fsx) << 3)];
            const s16x8 vh1 = *(const s16x8*)&VsHi[drow * 64 + (((4 + lg) ^ fsx) << 3)];
            const s16x8 vl1 = *(const s16x8*)&VsLo[drow * 64 + (((4 + lg) ^ fsx) << 3)];
#pragma unroll
            for (int miq = 0; miq < 2; ++miq) {
                if (t0 > qlo_w + miq * 16 + 15) continue;
                acc[miq][nt] = __builtin_amdgcn_mfma_f32_16x16x32_bf16(pa[miq][0], vh0, acc[miq][nt], 0, 0, 0);
                acc[miq][nt] = __builtin_amdgcn_mfma_f32_16x16x32_bf16(pa[miq][0], vl0, acc[miq][nt], 0, 0, 0);
                acc[miq][nt] = __builtin_amdgcn_mfma_f32_16x16x32_bf16(pa[miq][1], vh1, acc[miq][nt], 0, 0, 0);
                acc[miq][nt] = __builtin_amdgcn_mfma_f32_16x16x32_bf16(pa[miq][1], vl1, acc[miq][nt], 0, 0, 0);
            }
        }
    }

    // ---- epilogue: Z fp32 [b,s,D] ----
#pragma unroll
    for (int miq = 0; miq < 2; ++miq)
#pragma unroll
        for (int r = 0; r < 4; ++r) {
            const float inv = 1.f / lrun[miq][r];
            const int qg = q0b + w * 32 + miq * 16 + (lg << 2) + r;
            float* dst = &Z[(size_t)(b * Sn + qg) * Dn + h * HDn];
#pragma unroll
            for (int nt = 0; nt < 4; ++nt)
                dst[nt * 16 + l15] = acc[miq][nt][r] * inv;
        }
}

// ---------------------------------------------------------------------------
extern "C" void kernel_launch(void* const* d_in, const int* in_sizes, int n_in,
                              void* d_out, int out_size, void* d_ws, size_t ws_size,
                              hipStream_t stream)
{
    const float* x  = (const float*)d_in[0];
    // d_in[1] = causal mask — analytic
    const float* Wq = (const float*)d_in[2];
    const float* bq = (const float*)d_in[3];
    const float* Wk = (const float*)d_in[4];
    const float* bk = (const float*)d_in[5];
    const float* Wv = (const float*)d_in[6];
    const float* bv = (const float*)d_in[7];
    const float* Wo = (const float*)d_in[8];
    const float* bo = (const float*)d_in[9];
    float* out = (float*)d_out;

    char* ws = (char*)d_ws;
    float* Qf32 = (float*)ws;                       // 33,554,432 B (also Ztmp)
    short* Khi  = (short*)(ws + 33554432);          // 16,777,216 B
    short* Klo  = (short*)(ws + 50331648);
    short* Vthi = (short*)(ws + 67108864);
    short* Vtlo = (short*)(ws + 83886080);
    short* Whi  = (short*)(ws + 100663296);         //  2,097,152 B
    short* Wlo  = (short*)(ws + 102760448);         //  2,097,152 B -> total 104,857,600
    float* Ztmp = Qf32;                             // alias: Q dead after attn

    const int wn4 = Dn * Dn / 4;                    // 262144
    const dim3 gsplit(wn4 / 256);                   // 1024
    const dim3 gproj(Dn / 128, MROWS / 128);        // (8, 64)
    const dim3 gattn(Sn / 128, Hn, Bn);             // (16, 16, 4)

    split_planes<<<gsplit, 256, 0, stream>>>(Wq, Whi, Wlo, wn4);
    gemm_split<1><<<gproj, 256, 0, stream>>>(x, Whi, Wlo, bq, Qf32, nullptr, nullptr);
    split_planes<<<gsplit, 256, 0, stream>>>(Wk, Whi, Wlo, wn4);
    gemm_split<2><<<gproj, 256, 0, stream>>>(x, Whi, Wlo, bk, nullptr, Khi, Klo);
    split_planes<<<gsplit, 256, 0, stream>>>(Wv, Whi, Wlo, wn4);
    gemm_split<3><<<gproj, 256, 0, stream>>>(x, Whi, Wlo, bv, nullptr, Vthi, Vtlo);

    attn_fwd<<<gattn, 256, 0, stream>>>(Qf32, Khi, Klo, Vthi, Vtlo, out);

    split_planes<<<gsplit, 256, 0, stream>>>(Wo, Whi, Wlo, wn4);
    gemm_split<0><<<gproj, 256, 0, stream>>>(out, Whi, Wlo, bo, Ztmp, nullptr, nullptr);
    copy_f32<<<dim3(MROWS * Dn / 4 / 256), 256, 0, stream>>>(Ztmp, out, MROWS * Dn / 4);
}